// Round 1
// baseline (1834.090 us; speedup 1.0000x reference)
//
#include <hip/hip_runtime.h>
#include <math.h>

#define NN 100000
#define NE 1600000
#define H 128
#define LH 384
#define GG 512
#define CC 10
#define EPSBN 1e-5f

// ---------------- CSR build ----------------

__global__ void k_count(const int* __restrict__ dst, int* __restrict__ cnt, int e) {
    int i = blockIdx.x * blockDim.x + threadIdx.x;
    if (i < e) atomicAdd(&cnt[dst[i]], 1);
}

// per-1024-chunk exclusive prefix; chunk totals to bsum
__global__ void k_scan1(const int* __restrict__ cnt, int* __restrict__ pre,
                        int* __restrict__ bsum, int n) {
    __shared__ int sh[256];
    int t = threadIdx.x;
    int base = blockIdx.x * 1024 + t * 4;
    int v[4];
    int s = 0;
    for (int j = 0; j < 4; ++j) {
        int idx = base + j;
        v[j] = (idx < n) ? cnt[idx] : 0;
        s += v[j];
    }
    sh[t] = s;
    __syncthreads();
    for (int off = 1; off < 256; off <<= 1) {
        int x = (t >= off) ? sh[t - off] : 0;
        __syncthreads();
        sh[t] += x;
        __syncthreads();
    }
    int excl = sh[t] - s;
    if (t == 255) bsum[blockIdx.x] = sh[255];
    int run = excl;
    for (int j = 0; j < 4; ++j) {
        int idx = base + j;
        if (idx < n) pre[idx] = run;
        run += v[j];
    }
}

__global__ void k_scan2(const int* __restrict__ bsum, int* __restrict__ bpre, int nb) {
    if (threadIdx.x == 0 && blockIdx.x == 0) {
        int s = 0;
        for (int i = 0; i < nb; ++i) { bpre[i] = s; s += bsum[i]; }
    }
}

__global__ void k_scan3(int* __restrict__ pre, int* __restrict__ cursor,
                        const int* __restrict__ bpre, int n, int e) {
    int i = blockIdx.x * blockDim.x + threadIdx.x;
    if (i < n) {
        int v = pre[i] + bpre[i >> 10];
        pre[i] = v;
        cursor[i] = v;
    }
    if (i == 0) pre[n] = e;
}

__global__ void k_scatter(const int* __restrict__ src, const int* __restrict__ dst,
                          int* __restrict__ cursor, int* __restrict__ col, int e) {
    int i = blockIdx.x * blockDim.x + threadIdx.x;
    if (i < e) {
        int d = dst[i];
        int p = atomicAdd(&cursor[d], 1);
        col[p] = src[i];
    }
}

__global__ void k_dinv(const int* __restrict__ cnt, float* __restrict__ dinv, int n) {
    int i = blockIdx.x * blockDim.x + threadIdx.x;
    if (i < n) dinv[i] = rsqrtf((float)(cnt[i] + 1));  // +1 self-loop
}

// ---------------- GEMM: C[n,H] = A[n,lda offset] @ W[H,H] ----------------
// 64x64 tile, 16x16 threads, 4x4 micro-tile, K staged in 16-chunks.

__global__ void k_gemm(const float* __restrict__ A, int lda,
                       const float* __restrict__ W, float* __restrict__ Cmat, int n) {
    __shared__ float As[16][65];
    __shared__ float Bs[16][65];
    int tx = threadIdx.x & 15, ty = threadIdx.x >> 4;
    int rowBase = blockIdx.x * 64;
    int colBase = blockIdx.y * 64;
    float acc[4][4];
    for (int i = 0; i < 4; ++i)
        for (int j = 0; j < 4; ++j) acc[i][j] = 0.f;
    for (int k0 = 0; k0 < H; k0 += 16) {
        for (int i = threadIdx.x; i < 64 * 16; i += 256) {
            int r = i >> 4, kk = i & 15;
            int row = rowBase + r;
            As[kk][r] = (row < n) ? A[(size_t)row * lda + k0 + kk] : 0.f;
        }
        for (int i = threadIdx.x; i < 64 * 16; i += 256) {
            int kk = i >> 6, c = i & 63;
            Bs[kk][c] = W[(k0 + kk) * H + colBase + c];
        }
        __syncthreads();
        for (int kk = 0; kk < 16; ++kk) {
            float a[4], b[4];
            for (int i = 0; i < 4; ++i) a[i] = As[kk][ty * 4 + i];
            for (int j = 0; j < 4; ++j) b[j] = Bs[kk][tx * 4 + j];
            for (int i = 0; i < 4; ++i)
                for (int j = 0; j < 4; ++j) acc[i][j] += a[i] * b[j];
        }
        __syncthreads();
    }
    for (int i = 0; i < 4; ++i) {
        int row = rowBase + ty * 4 + i;
        if (row < n)
            for (int j = 0; j < 4; ++j)
                Cmat[(size_t)row * H + colBase + tx * 4 + j] = acc[i][j];
    }
}

// ---------------- Aggregation (pull / CSR gather) ----------------
// out[d,f] = dinv[d] * ( dinv[d]*hw[d,f] + sum_s dinv[s]*hw[s,f] ) + bias[f]

__global__ void k_agg(const float* __restrict__ hw, const int* __restrict__ rp,
                      const int* __restrict__ col, const float* __restrict__ dinv,
                      const float* __restrict__ bias, float* __restrict__ out, int n) {
    int node = blockIdx.x * 2 + (threadIdx.x >> 7);
    int f = threadIdx.x & 127;
    if (node >= n) return;
    float dn = dinv[node];
    float acc = dn * hw[(size_t)node * H + f];  // self-loop
    int s0 = rp[node], s1 = rp[node + 1];
    for (int p = s0; p < s1; ++p) {
        int s = col[p];
        acc += dinv[s] * hw[(size_t)s * H + f];
    }
    out[(size_t)node * H + f] = dn * acc + bias[f];
}

// ---------------- BatchNorm ----------------

__global__ void k_bnstats(const float* __restrict__ a, float* __restrict__ stats, int n) {
    __shared__ float ssum[256], ssq[256];
    int f = threadIdx.x & 127;
    int rg = threadIdx.x >> 7;
    int rEnd = blockIdx.x * 256 + 256;
    if (rEnd > n) rEnd = n;
    float s = 0.f, q = 0.f;
    for (int r = blockIdx.x * 256 + rg; r < rEnd; r += 2) {
        float v = a[(size_t)r * H + f];
        s += v;
        q += v * v;
    }
    ssum[threadIdx.x] = s;
    ssq[threadIdx.x] = q;
    __syncthreads();
    if (rg == 0) {
        s += ssum[threadIdx.x + 128];
        q += ssq[threadIdx.x + 128];
        atomicAdd(&stats[f], s);
        atomicAdd(&stats[128 + f], q);
    }
}

__global__ void k_bnapply(const float* __restrict__ a, const float* __restrict__ stats,
                          const float* __restrict__ g, const float* __restrict__ bt,
                          float* __restrict__ out, int n, int ldo) {
    int i = blockIdx.x * blockDim.x + threadIdx.x;
    if (i >= n * H) return;
    int f = i & 127;
    int r = i >> 7;
    float inv_n = 1.0f / (float)n;
    float mu = stats[f] * inv_n;
    float var = stats[128 + f] * inv_n - mu * mu;
    float v = (a[i] - mu) * rsqrtf(var + EPSBN) * g[f] + bt[f];
    out[(size_t)r * ldo + f] = fmaxf(v, 0.f);
}

// ---------------- Pooling ----------------

__global__ void k_gcount(const int* __restrict__ batch, int* __restrict__ gcnt, int n) {
    int i = blockIdx.x * blockDim.x + threadIdx.x;
    if (i < n) atomicAdd(&gcnt[batch[i]], 1);
}

__global__ void k_gscan(const int* __restrict__ gcnt, int* __restrict__ gptr) {
    if (threadIdx.x == 0 && blockIdx.x == 0) {
        int s = 0;
        for (int g = 0; g < GG; ++g) { gptr[g] = s; s += gcnt[g]; }
        gptr[GG] = s;
    }
}

__global__ void k_pool(const float* __restrict__ hcat, const int* __restrict__ gptr,
                       float* __restrict__ pooled) {
    int g = blockIdx.x;
    int f = threadIdx.x;  // 384 threads
    int r0 = gptr[g], r1 = gptr[g + 1];
    float s = 0.f;
    for (int r = r0; r < r1; ++r) s += hcat[(size_t)r * LH + f];
    float c = (float)(r1 - r0);
    pooled[g * LH + f] = s / fmaxf(c, 1.f);
}

// ---------------- MLP head ----------------

__global__ void k_mlp1(const float* __restrict__ pooled, const float* __restrict__ Wl1,
                       const float* __restrict__ bl1, float* __restrict__ z) {
    __shared__ float row[LH];
    int g = blockIdx.x;
    int j = threadIdx.x;  // 128 threads
    for (int k = j; k < LH; k += H) row[k] = pooled[g * LH + k];
    __syncthreads();
    float acc = bl1[j];
    for (int k = 0; k < LH; ++k) acc += row[k] * Wl1[k * H + j];
    z[g * H + j] = acc;
}

__global__ void k_zstats(const float* __restrict__ z, float* __restrict__ st) {
    int j = threadIdx.x;  // 128 threads, 1 block
    float s = 0.f, q = 0.f;
    for (int g = 0; g < GG; ++g) {
        float v = z[g * H + j];
        s += v;
        q += v * v;
    }
    st[j] = s;
    st[128 + j] = q;
}

__global__ void k_mlp2(const float* __restrict__ z, const float* __restrict__ st,
                       const float* __restrict__ gl, const float* __restrict__ btl,
                       const float* __restrict__ Wl2, const float* __restrict__ bl2,
                       float* __restrict__ out) {
    __shared__ float zn[H];
    __shared__ float logit[CC];
    int g = blockIdx.x;
    int t = threadIdx.x;  // 128 threads
    float mu = st[t] * (1.f / GG);
    float var = st[128 + t] * (1.f / GG) - mu * mu;
    float v = (z[g * H + t] - mu) * rsqrtf(var + EPSBN) * gl[t] + btl[t];
    zn[t] = fmaxf(v, 0.f);
    __syncthreads();
    if (t < CC) {
        float acc = bl2[t];
        for (int k = 0; k < H; ++k) acc += zn[k] * Wl2[k * CC + t];
        logit[t] = acc;
    }
    __syncthreads();
    if (t == 0) {
        float m = -1e30f;
        for (int c = 0; c < CC; ++c) m = fmaxf(m, logit[c]);
        float se = 0.f;
        for (int c = 0; c < CC; ++c) se += expf(logit[c] - m);
        float lse = m + logf(se);
        for (int c = 0; c < CC; ++c) out[g * CC + c] = logit[c] - lse;
    }
}

// ---------------- launch ----------------

extern "C" void kernel_launch(void* const* d_in, const int* in_sizes, int n_in,
                              void* d_out, int out_size, void* d_ws, size_t ws_size,
                              hipStream_t stream) {
    const float* x   = (const float*)d_in[0];
    const int*   ei  = (const int*)d_in[1];
    const int*   bat = (const int*)d_in[2];
    const float* W1  = (const float*)d_in[3];
    const float* b1  = (const float*)d_in[4];
    const float* g1  = (const float*)d_in[5];
    const float* bt1 = (const float*)d_in[6];
    const float* Wc  = (const float*)d_in[7];
    const float* bc  = (const float*)d_in[8];
    const float* gc  = (const float*)d_in[9];
    const float* btc = (const float*)d_in[10];
    const float* Wl1 = (const float*)d_in[11];
    const float* bl1 = (const float*)d_in[12];
    const float* gl  = (const float*)d_in[13];
    const float* btl = (const float*)d_in[14];
    const float* Wl2 = (const float*)d_in[15];
    const float* bl2 = (const float*)d_in[16];
    float* out = (float*)d_out;

    const int n = in_sizes[2];       // N nodes
    const int e = in_sizes[1] / 2;   // E edges
    const int* src = ei;
    const int* dst = ei + e;

    // workspace carve-up (256B aligned)
    size_t off = 0;
    char* base = (char*)d_ws;
    auto take = [&](size_t nbytes) -> void* {
        void* p = base + off;
        off += (nbytes + 255) & ~(size_t)255;
        return p;
    };
    int*   cnt    = (int*)take((size_t)NN * 4);
    int*   rp     = (int*)take((size_t)(NN + 1) * 4);
    int*   cursor = (int*)take((size_t)NN * 4);
    int*   col    = (int*)take((size_t)NE * 4);
    int*   bsum   = (int*)take(1024);
    int*   bpre   = (int*)take(1024);
    float* dinv   = (float*)take((size_t)NN * 4);
    float* stats  = (float*)take(1024);
    int*   gcnt   = (int*)take((size_t)GG * 4);
    int*   gptr   = (int*)take((size_t)(GG + 1) * 4);
    float* hw     = (float*)take((size_t)NN * H * 4);
    float* agg    = (float*)take((size_t)NN * H * 4);
    float* hcat   = (float*)take((size_t)NN * LH * 4);
    float* pooled = (float*)take((size_t)GG * LH * 4);
    float* z      = (float*)take((size_t)GG * H * 4);
    float* zst    = (float*)take(1024);

    const int nb = (n + 1023) / 1024;

    // ---- CSR build ----
    hipMemsetAsync(cnt, 0, (size_t)n * 4, stream);
    k_count<<<(e + 255) / 256, 256, 0, stream>>>(dst, cnt, e);
    k_scan1<<<nb, 256, 0, stream>>>(cnt, rp, bsum, n);
    k_scan2<<<1, 64, 0, stream>>>(bsum, bpre, nb);
    k_scan3<<<(n + 255) / 256, 256, 0, stream>>>(rp, cursor, bpre, n, e);
    k_scatter<<<(e + 255) / 256, 256, 0, stream>>>(src, dst, cursor, col, e);
    k_dinv<<<(n + 255) / 256, 256, 0, stream>>>(cnt, dinv, n);

    // ---- 3 GCN layers ----
    for (int l = 0; l < 3; ++l) {
        const float* A   = (l == 0) ? x : (hcat + (size_t)(l - 1) * H);
        int lda          = (l == 0) ? H : LH;
        const float* Wm  = (l == 0) ? W1 : (Wc + (size_t)(l - 1) * H * H);
        const float* bm  = (l == 0) ? b1 : (bc + (size_t)(l - 1) * H);
        const float* gm  = (l == 0) ? g1 : (gc + (size_t)(l - 1) * H);
        const float* btm = (l == 0) ? bt1 : (btc + (size_t)(l - 1) * H);

        dim3 ggrid((n + 63) / 64, 2);
        k_gemm<<<ggrid, 256, 0, stream>>>(A, lda, Wm, hw, n);
        k_agg<<<(n + 1) / 2, 256, 0, stream>>>(hw, rp, col, dinv, bm, agg, n);
        hipMemsetAsync(stats, 0, 1024, stream);
        k_bnstats<<<(n + 255) / 256, 256, 0, stream>>>(agg, stats, n);
        k_bnapply<<<((size_t)n * H + 255) / 256, 256, 0, stream>>>(
            agg, stats, gm, btm, hcat + (size_t)l * H, n, LH);
    }

    // ---- pooling ----
    hipMemsetAsync(gcnt, 0, (size_t)GG * 4, stream);
    k_gcount<<<(n + 255) / 256, 256, 0, stream>>>(bat, gcnt, n);
    k_gscan<<<1, 64, 0, stream>>>(gcnt, gptr);
    k_pool<<<GG, LH, 0, stream>>>(hcat, gptr, pooled);

    // ---- MLP head ----
    k_mlp1<<<GG, H, 0, stream>>>(pooled, Wl1, bl1, z);
    k_zstats<<<1, H, 0, stream>>>(z, zst);
    k_mlp2<<<GG, H, 0, stream>>>(z, zst, gl, btl, Wl2, bl2, out);
}

// Round 2
// 1110.555 us; speedup vs baseline: 1.6515x; 1.6515x over previous
//
#include <hip/hip_runtime.h>
#include <math.h>

#define NN 100000
#define NE 1600000
#define H 128
#define LH 384
#define GG 512
#define CC 10
#define EPSBN 1e-5f

typedef __attribute__((ext_vector_type(4))) float f32x4;
typedef __attribute__((ext_vector_type(8))) short s16x8;

__device__ inline ushort f2b(float f) {
    uint u = __float_as_uint(f);
    uint r = (u + 0x7FFFu + ((u >> 16) & 1u)) >> 16;
    return (ushort)r;
}
__device__ inline float b2f(ushort b) { return __uint_as_float(((uint)b) << 16); }
__device__ inline float blo(uint v) { return __uint_as_float(v << 16); }
__device__ inline float bhi(uint v) { return __uint_as_float(v & 0xFFFF0000u); }

// ---------------- fp32 -> bf16 conversion ----------------

__global__ void k_cvt(const float* __restrict__ in, ushort* __restrict__ outp, int count) {
    int i = (blockIdx.x * blockDim.x + threadIdx.x) * 4;
    if (i + 4 <= count) {
        float4 v = *(const float4*)(in + i);
        ushort4 o;
        o.x = f2b(v.x); o.y = f2b(v.y); o.z = f2b(v.z); o.w = f2b(v.w);
        *(ushort4*)(outp + i) = o;
    } else {
        for (; i < count; ++i) outp[i] = f2b(in[i]);
    }
}

// ---------------- CSR build ----------------

__global__ void k_count(const int* __restrict__ dst, int* __restrict__ cnt, int e) {
    int i = blockIdx.x * blockDim.x + threadIdx.x;
    if (i < e) atomicAdd(&cnt[dst[i]], 1);
}

__global__ void k_scan1(const int* __restrict__ cnt, int* __restrict__ pre,
                        int* __restrict__ bsum, int n) {
    __shared__ int sh[256];
    int t = threadIdx.x;
    int base = blockIdx.x * 1024 + t * 4;
    int v[4];
    int s = 0;
    for (int j = 0; j < 4; ++j) {
        int idx = base + j;
        v[j] = (idx < n) ? cnt[idx] : 0;
        s += v[j];
    }
    sh[t] = s;
    __syncthreads();
    for (int off = 1; off < 256; off <<= 1) {
        int x = (t >= off) ? sh[t - off] : 0;
        __syncthreads();
        sh[t] += x;
        __syncthreads();
    }
    int excl = sh[t] - s;
    if (t == 255) bsum[blockIdx.x] = sh[255];
    int run = excl;
    for (int j = 0; j < 4; ++j) {
        int idx = base + j;
        if (idx < n) pre[idx] = run;
        run += v[j];
    }
}

__global__ void k_scan2(const int* __restrict__ bsum, int* __restrict__ bpre, int nb) {
    if (threadIdx.x == 0 && blockIdx.x == 0) {
        int s = 0;
        for (int i = 0; i < nb; ++i) { bpre[i] = s; s += bsum[i]; }
    }
}

__global__ void k_scan3(int* __restrict__ pre, int* __restrict__ cursor,
                        const int* __restrict__ bpre, int n, int e) {
    int i = blockIdx.x * blockDim.x + threadIdx.x;
    if (i < n) {
        int v = pre[i] + bpre[i >> 10];
        pre[i] = v;
        cursor[i] = v;
    }
    if (i == 0) pre[n] = e;
}

__global__ void k_scatter(const int* __restrict__ src, const int* __restrict__ dst,
                          int* __restrict__ cursor, int* __restrict__ col, int e) {
    int i = blockIdx.x * blockDim.x + threadIdx.x;
    if (i < e) {
        int d = dst[i];
        int p = atomicAdd(&cursor[d], 1);
        col[p] = src[i];
    }
}

__global__ void k_dinv(const int* __restrict__ cnt, float* __restrict__ dinv, int n) {
    int i = blockIdx.x * blockDim.x + threadIdx.x;
    if (i < n) dinv[i] = rsqrtf((float)(cnt[i] + 1));  // +1 self-loop
}

// ---------------- MFMA GEMM: C[n,128]bf16 = A[n,lda]bf16 @ W[128,128]bf16 ----
// block = 256 threads (4 waves); tile = 64 rows x 128 cols; each wave: 16 rows.

__global__ __launch_bounds__(256) void k_gemm_mfma(
    const ushort* __restrict__ A, int lda, const ushort* __restrict__ Wb,
    ushort* __restrict__ Cout, int n) {
    __shared__ ushort As[64][136];   // +8 pad: row stride 272B -> 2-way max
    __shared__ ushort Ws[128][136];  // transposed: Ws[n][k]
    int t = threadIdx.x;
    int wave = t >> 6, lane = t & 63;
    int rowBase = blockIdx.x * 64;

    // stage A (64 x 128 bf16), 16B chunks
    for (int i = t; i < 64 * 16; i += 256) {
        int r = i >> 4, c8 = i & 15;
        int row = rowBase + r;
        uint4 v = make_uint4(0u, 0u, 0u, 0u);
        if (row < n) v = *(const uint4*)(A + (size_t)row * lda + c8 * 8);
        *(uint4*)(&As[r][c8 * 8]) = v;
    }
    // stage W transposed
    for (int i = t; i < 128 * 16; i += 256) {
        int k = i >> 4, c8 = i & 15;
        uint4 v = *(const uint4*)(Wb + k * 128 + c8 * 8);
        const ushort* pv = (const ushort*)&v;
#pragma unroll
        for (int j = 0; j < 8; ++j) Ws[c8 * 8 + j][k] = pv[j];
    }
    __syncthreads();

    int m = lane & 15, q = lane >> 4;
    f32x4 acc[8];
#pragma unroll
    for (int c = 0; c < 8; ++c) acc[c] = (f32x4){0.f, 0.f, 0.f, 0.f};
#pragma unroll
    for (int kc = 0; kc < 4; ++kc) {
        int kof = kc * 32 + q * 8;
        s16x8 afrag = *(const s16x8*)(&As[wave * 16 + m][kof]);
#pragma unroll
        for (int c = 0; c < 8; ++c) {
            s16x8 bfrag = *(const s16x8*)(&Ws[c * 16 + m][kof]);
            acc[c] = __builtin_amdgcn_mfma_f32_16x16x32_bf16(afrag, bfrag, acc[c], 0, 0, 0);
        }
    }
    // epilogue: D row = q*4+reg, col = c*16+m
#pragma unroll
    for (int c = 0; c < 8; ++c) {
        int col = c * 16 + m;
#pragma unroll
        for (int r = 0; r < 4; ++r) {
            int row = rowBase + wave * 16 + q * 4 + r;
            if (row < n) Cout[(size_t)row * H + col] = f2b(acc[c][r]);
        }
    }
}

// ---------------- Aggregation: one wave per node, bf16x2 per lane ----------

__global__ void k_agg(const ushort* __restrict__ hwb, const int* __restrict__ rp,
                      const int* __restrict__ col, const float* __restrict__ dinv,
                      const float* __restrict__ bias, float* __restrict__ out, int n) {
    int node = blockIdx.x * 4 + (threadIdx.x >> 6);
    int lane = threadIdx.x & 63;
    if (node >= n) return;
    const uint* hw32 = (const uint*)hwb;
    float dn = dinv[node];
    uint sv = hw32[(size_t)node * 64 + lane];
    float a0 = dn * blo(sv), a1 = dn * bhi(sv);  // self-loop
    int s0 = rp[node], s1 = rp[node + 1];
    int p = s0;
    for (; p + 2 <= s1; p += 2) {
        int sA = col[p], sB = col[p + 1];
        float dA = dinv[sA], dB = dinv[sB];
        uint vA = hw32[(size_t)sA * 64 + lane];
        uint vB = hw32[(size_t)sB * 64 + lane];
        a0 += dA * blo(vA) + dB * blo(vB);
        a1 += dA * bhi(vA) + dB * bhi(vB);
    }
    if (p < s1) {
        int sA = col[p];
        float dA = dinv[sA];
        uint vA = hw32[(size_t)sA * 64 + lane];
        a0 += dA * blo(vA);
        a1 += dA * bhi(vA);
    }
    int f = lane * 2;
    float2 o;
    o.x = dn * a0 + bias[f];
    o.y = dn * a1 + bias[f + 1];
    *(float2*)(out + (size_t)node * H + f) = o;
}

// ---------------- BatchNorm ----------------

__global__ void k_bnstats(const float* __restrict__ a, float* __restrict__ stats, int n) {
    __shared__ float ssum[256], ssq[256];
    int f = threadIdx.x & 127;
    int rg = threadIdx.x >> 7;
    int rEnd = blockIdx.x * 256 + 256;
    if (rEnd > n) rEnd = n;
    float s = 0.f, q = 0.f;
    for (int r = blockIdx.x * 256 + rg; r < rEnd; r += 2) {
        float v = a[(size_t)r * H + f];
        s += v;
        q += v * v;
    }
    ssum[threadIdx.x] = s;
    ssq[threadIdx.x] = q;
    __syncthreads();
    if (rg == 0) {
        s += ssum[threadIdx.x + 128];
        q += ssq[threadIdx.x + 128];
        atomicAdd(&stats[f], s);
        atomicAdd(&stats[128 + f], q);
    }
}

// BN-apply + ReLU, writes bf16 into the concat buffer
__global__ void k_bnapply(const float* __restrict__ a, const float* __restrict__ stats,
                          const float* __restrict__ g, const float* __restrict__ bt,
                          ushort* __restrict__ outp, int n, int ldo) {
    int i = blockIdx.x * blockDim.x + threadIdx.x;
    if (i >= n * H) return;
    int f = i & 127;
    int r = i >> 7;
    float inv_n = 1.0f / (float)n;
    float mu = stats[f] * inv_n;
    float var = stats[128 + f] * inv_n - mu * mu;
    float v = (a[i] - mu) * rsqrtf(var + EPSBN) * g[f] + bt[f];
    outp[(size_t)r * ldo + f] = f2b(fmaxf(v, 0.f));
}

// ---------------- Pooling ----------------

__global__ void k_gcount(const int* __restrict__ batch, int* __restrict__ gcnt, int n) {
    int i = blockIdx.x * blockDim.x + threadIdx.x;
    if (i < n) atomicAdd(&gcnt[batch[i]], 1);
}

__global__ void k_gscan(const int* __restrict__ gcnt, int* __restrict__ gptr) {
    if (threadIdx.x == 0 && blockIdx.x == 0) {
        int s = 0;
        for (int g = 0; g < GG; ++g) { gptr[g] = s; s += gcnt[g]; }
        gptr[GG] = s;
    }
}

__global__ void k_pool(const ushort* __restrict__ hcat, const int* __restrict__ gptr,
                       float* __restrict__ pooled) {
    int g = blockIdx.x;
    int f = threadIdx.x;  // 384 threads
    int r0 = gptr[g], r1 = gptr[g + 1];
    float s = 0.f;
    for (int r = r0; r < r1; ++r) s += b2f(hcat[(size_t)r * LH + f]);
    float c = (float)(r1 - r0);
    pooled[g * LH + f] = s / fmaxf(c, 1.f);
}

// ---------------- MLP head ----------------

__global__ void k_mlp1(const float* __restrict__ pooled, const float* __restrict__ Wl1,
                       const float* __restrict__ bl1, float* __restrict__ z) {
    __shared__ float row[LH];
    int g = blockIdx.x;
    int j = threadIdx.x;  // 128 threads
    for (int k = j; k < LH; k += H) row[k] = pooled[g * LH + k];
    __syncthreads();
    float acc = bl1[j];
    for (int k = 0; k < LH; ++k) acc += row[k] * Wl1[k * H + j];
    z[g * H + j] = acc;
}

__global__ void k_zstats(const float* __restrict__ z, float* __restrict__ st) {
    int j = threadIdx.x;  // 128 threads, 1 block
    float s = 0.f, q = 0.f;
    for (int g = 0; g < GG; ++g) {
        float v = z[g * H + j];
        s += v;
        q += v * v;
    }
    st[j] = s;
    st[128 + j] = q;
}

__global__ void k_mlp2(const float* __restrict__ z, const float* __restrict__ st,
                       const float* __restrict__ gl, const float* __restrict__ btl,
                       const float* __restrict__ Wl2, const float* __restrict__ bl2,
                       float* __restrict__ out) {
    __shared__ float zn[H];
    __shared__ float logit[CC];
    int g = blockIdx.x;
    int t = threadIdx.x;  // 128 threads
    float mu = st[t] * (1.f / GG);
    float var = st[128 + t] * (1.f / GG) - mu * mu;
    float v = (z[g * H + t] - mu) * rsqrtf(var + EPSBN) * gl[t] + btl[t];
    zn[t] = fmaxf(v, 0.f);
    __syncthreads();
    if (t < CC) {
        float acc = bl2[t];
        for (int k = 0; k < H; ++k) acc += zn[k] * Wl2[k * CC + t];
        logit[t] = acc;
    }
    __syncthreads();
    if (t == 0) {
        float m = -1e30f;
        for (int c = 0; c < CC; ++c) m = fmaxf(m, logit[c]);
        float se = 0.f;
        for (int c = 0; c < CC; ++c) se += expf(logit[c] - m);
        float lse = m + logf(se);
        for (int c = 0; c < CC; ++c) out[g * CC + c] = logit[c] - lse;
    }
}

// ---------------- launch ----------------

extern "C" void kernel_launch(void* const* d_in, const int* in_sizes, int n_in,
                              void* d_out, int out_size, void* d_ws, size_t ws_size,
                              hipStream_t stream) {
    const float* x   = (const float*)d_in[0];
    const int*   ei  = (const int*)d_in[1];
    const int*   bat = (const int*)d_in[2];
    const float* W1  = (const float*)d_in[3];
    const float* b1  = (const float*)d_in[4];
    const float* g1  = (const float*)d_in[5];
    const float* bt1 = (const float*)d_in[6];
    const float* Wc  = (const float*)d_in[7];
    const float* bc  = (const float*)d_in[8];
    const float* gc  = (const float*)d_in[9];
    const float* btc = (const float*)d_in[10];
    const float* Wl1 = (const float*)d_in[11];
    const float* bl1 = (const float*)d_in[12];
    const float* gl  = (const float*)d_in[13];
    const float* btl = (const float*)d_in[14];
    const float* Wl2 = (const float*)d_in[15];
    const float* bl2 = (const float*)d_in[16];
    float* out = (float*)d_out;

    const int n = in_sizes[2];
    const int e = in_sizes[1] / 2;
    const int* src = ei;
    const int* dst = ei + e;

    size_t off = 0;
    char* base = (char*)d_ws;
    auto take = [&](size_t nbytes) -> void* {
        void* p = base + off;
        off += (nbytes + 255) & ~(size_t)255;
        return p;
    };
    int*    cnt    = (int*)take((size_t)NN * 4);
    int*    rp     = (int*)take((size_t)(NN + 1) * 4);
    int*    cursor = (int*)take((size_t)NN * 4);
    int*    col    = (int*)take((size_t)NE * 4);
    int*    bsum   = (int*)take(1024);
    int*    bpre   = (int*)take(1024);
    float*  dinv   = (float*)take((size_t)NN * 4);
    float*  stats  = (float*)take(1024);
    int*    gcnt   = (int*)take((size_t)GG * 4);
    int*    gptr   = (int*)take((size_t)(GG + 1) * 4);
    ushort* xb     = (ushort*)take((size_t)NN * H * 2);
    ushort* W1b    = (ushort*)take((size_t)H * H * 2);
    ushort* Wcb    = (ushort*)take((size_t)2 * H * H * 2);
    ushort* hwb    = (ushort*)take((size_t)NN * H * 2);
    float*  agg    = (float*)take((size_t)NN * H * 4);
    ushort* hcatb  = (ushort*)take((size_t)NN * LH * 2);
    float*  pooled = (float*)take((size_t)GG * LH * 4);
    float*  z      = (float*)take((size_t)GG * H * 4);
    float*  zst    = (float*)take(1024);

    const int nb = (n + 1023) / 1024;

    // ---- conversions ----
    {
        int cn = n * H;
        k_cvt<<<(cn / 4 + 255) / 256, 256, 0, stream>>>(x, xb, cn);
        k_cvt<<<(H * H / 4 + 255) / 256, 256, 0, stream>>>(W1, W1b, H * H);
        k_cvt<<<(2 * H * H / 4 + 255) / 256, 256, 0, stream>>>(Wc, Wcb, 2 * H * H);
    }

    // ---- CSR build ----
    hipMemsetAsync(cnt, 0, (size_t)n * 4, stream);
    k_count<<<(e + 255) / 256, 256, 0, stream>>>(dst, cnt, e);
    k_scan1<<<nb, 256, 0, stream>>>(cnt, rp, bsum, n);
    k_scan2<<<1, 64, 0, stream>>>(bsum, bpre, nb);
    k_scan3<<<(n + 255) / 256, 256, 0, stream>>>(rp, cursor, bpre, n, e);
    k_scatter<<<(e + 255) / 256, 256, 0, stream>>>(src, dst, cursor, col, e);
    k_dinv<<<(n + 255) / 256, 256, 0, stream>>>(cnt, dinv, n);

    // ---- 3 GCN layers ----
    for (int l = 0; l < 3; ++l) {
        const ushort* A   = (l == 0) ? xb : (hcatb + (size_t)(l - 1) * H);
        int lda           = (l == 0) ? H : LH;
        const ushort* Wm  = (l == 0) ? W1b : (Wcb + (size_t)(l - 1) * H * H);
        const float*  bm  = (l == 0) ? b1 : (bc + (size_t)(l - 1) * H);
        const float*  gm  = (l == 0) ? g1 : (gc + (size_t)(l - 1) * H);
        const float*  btm = (l == 0) ? bt1 : (btc + (size_t)(l - 1) * H);

        k_gemm_mfma<<<(n + 63) / 64, 256, 0, stream>>>(A, lda, Wm, hwb, n);
        k_agg<<<(n + 3) / 4, 256, 0, stream>>>(hwb, rp, col, dinv, bm, agg, n);
        hipMemsetAsync(stats, 0, 1024, stream);
        k_bnstats<<<(n + 255) / 256, 256, 0, stream>>>(agg, stats, n);
        k_bnapply<<<((size_t)n * H + 255) / 256, 256, 0, stream>>>(
            agg, stats, gm, btm, hcatb + (size_t)l * H, n, LH);
    }

    // ---- pooling ----
    hipMemsetAsync(gcnt, 0, (size_t)GG * 4, stream);
    k_gcount<<<(n + 255) / 256, 256, 0, stream>>>(bat, gcnt, n);
    k_gscan<<<1, 64, 0, stream>>>(gcnt, gptr);
    k_pool<<<GG, LH, 0, stream>>>(hcatb, gptr, pooled);

    // ---- MLP head ----
    k_mlp1<<<GG, H, 0, stream>>>(pooled, Wl1, bl1, z);
    k_zstats<<<1, H, 0, stream>>>(z, zst);
    k_mlp2<<<GG, H, 0, stream>>>(z, zst, gl, btl, Wl2, bl2, out);
}